// Round 9
// baseline (60.930 us; speedup 1.0000x reference)
//
#include <hip/hip_runtime.h>
#include <math.h>

#define NW 11
#define NL 8
#define NPIX 1024

typedef float f2 __attribute__((ext_vector_type(2)));
typedef float f4 __attribute__((ext_vector_type(4)));

struct FTab { int C[NL][NW]; };   // C[l][b] = F_l(1<<b), composed CNOT ring

// Composed CNOT-ring permutation (validated rounds 1-6): ascending q,
// m ^= ((m>>pc)&1)<<pt, pc=10-q, pt=10-((q+r)%11).
static inline int fmap_h(int m, int r) {
    for (int q = 0; q < NW; ++q) {
        int pc = 10 - q;
        int qq = q + r; if (qq >= NW) qq -= NW;
        int pt = 10 - qq;
        m ^= ((m >> pc) & 1) << pt;
    }
    return m;
}

#define FMA2 __builtin_elementwise_fma

// ---- DPP lane-xor helpers (VALU pipe, no LDS) ----
template<int CTRL>
__device__ __forceinline__ float dpp_f(float x) {
    int xi = __float_as_int(x);
    int r  = __builtin_amdgcn_update_dpp(xi, xi, CTRL, 0xF, 0xF, false);
    return __int_as_float(r);
}
template<int CTRL>
__device__ __forceinline__ f2 dpp2(f2 v) {
    return (f2){dpp_f<CTRL>(v.x), dpp_f<CTRL>(v.y)};
}

// partner fetch for lane-bit butterflies
// MODE 0: lane^8 (row_ror:8)  1: lane^4 (row_shl4/shr4+sel)
// MODE 2: lane^2 (quad_perm)  3: lane^1 (quad_perm)
// AMD DPP convention (per GCN scan idiom): row_shr:N -> src[L-N],
// row_shl:N -> src[L+N]. (Round-7/8 bug: this select was inverted.)
template<int MODE>
__device__ __forceinline__ f2 bfetch(f2 v, int L) {
    if constexpr (MODE == 0) return dpp2<0x128>(v);       // row_ror:8 = lane^8
    else if constexpr (MODE == 1) {
        f2 fwd = dpp2<0x104>(v);   // row_shl:4 -> src[L+4]
        f2 bwd = dpp2<0x114>(v);   // row_shr:4 -> src[L-4]
        return (L & 4) ? bwd : fwd;
    }
    else if constexpr (MODE == 2) return dpp2<0x4E>(v);   // quad[2,3,0,1]
    else return dpp2<0xB1>(v);                            // quad[1,0,3,2]
}

// ---- reg<->lane bit swaps ----
// swap32: exchange a@(L5=1) with b@(L5=0) via v_permlane32_swap_b32
// (proven equivalent to the shfl_xor form: rounds 7 and 8 bit-identical).
__device__ __forceinline__ void swap32(f2& a, f2& b) {
    float ax = a.x, ay = a.y, bx = b.x, by = b.y;
    asm volatile("v_permlane32_swap_b32 %0, %1" : "+v"(ax), "+v"(bx));
    asm volatile("v_permlane32_swap_b32 %0, %1" : "+v"(ay), "+v"(by));
    a = (f2){ax, ay}; b = (f2){bx, by};
}
// orientation-safe swap via shfl_xor: each lane sends what its partner needs.
__device__ __forceinline__ void swapX(f2& a, f2& b, bool hi, int mask) {
    float sx = hi ? a.x : b.x;
    float sy = hi ? a.y : b.y;
    f2 t = (f2){__shfl_xor(sx, mask, 64), __shfl_xor(sy, mask, 64)};
    a = hi ? t : a;
    b = hi ? b : t;
}

// ---- gate on a register-resident bit (pairing mask M), packed complex ----
// g: {(u00r,u00r),(-u00i,u00i),(u01r,u01r),(-u01i,u01i),
//     (u10r,u10r),(-u10i,u10i),(u11r,u11r),(-u11i,u11i)}
template<int M>
__device__ __forceinline__ void gateR(f2 (&X)[32], const f2* __restrict__ g) {
    const f2 c0 = g[0], c1 = g[1], c2 = g[2], c3 = g[3];
    const f2 c4 = g[4], c5 = g[5], c6 = g[6], c7 = g[7];
    #pragma unroll
    for (int s = 0; s < 32; ++s) {
        if (s & M) continue;
        const int s1 = s | M;
        f2 v0 = X[s], v1 = X[s1];
        f2 v0y = v0.yx, v1y = v1.yx;
        X[s]  = FMA2(c3, v1y, FMA2(c2, v1, FMA2(c1, v0y, c0 * v0)));
        X[s1] = FMA2(c7, v1y, FMA2(c6, v1, FMA2(c5, v0y, c4 * v0)));
    }
}

// ---- gate on a lane-resident bit via DPP butterfly exchange ----
template<int LBIT, int MODE>
__device__ __forceinline__ void gateL(f2 (&X)[32], const f2* __restrict__ g, int L) {
    const bool sb = (L >> LBIT) & 1;
    const f2 a0 = sb ? g[6] : g[0], a1 = sb ? g[7] : g[1];
    const f2 b0 = sb ? g[4] : g[2], b1 = sb ? g[5] : g[3];
    #pragma unroll
    for (int s = 0; s < 32; ++s) {
        f2 v = X[s];
        f2 p = bfetch<MODE>(v, L);
        f2 vy = v.yx, py = p.yx;
        X[s] = FMA2(b1, py, FMA2(b0, p, FMA2(a1, vy, a0 * v)));
    }
}

// ---- one wave (64 threads) per batch element; state in 32 f2 regs/lane.
// Canonical layout: reg bits j4..j0 = amp bits 10..6; lanes L5..L0 = amp 5..0.
// No __syncthreads anywhere (single wave); LDS used only for the per-layer
// CNOT permutation scatter + coefficient broadcast + psi staging.
__global__ __launch_bounds__(64) void pqc_kernel(
    const float* __restrict__ image, const float* __restrict__ label,
    const float* __restrict__ weights, float* __restrict__ out, FTab ft)
{
    __shared__ __align__(16) f2 sS[2048];        // state scatter buffer (16 KB)
    __shared__ __align__(16) f2 sG[NL * NW * 8]; // 88 gates x 8 f2 (5.5 KB)

    const int b = blockIdx.x, L = threadIdx.x;

    // ---- Rot gate matrices into LDS (per-wave, redundant across blocks) ----
    for (int t = L; t < NL * NW; t += 64) {
        const float* w = weights + t * 3;
        const float PI = 3.14159265358979323846f;
        float phi   = PI * tanhf(w[0]);
        float theta = PI * tanhf(w[1]);
        float omega = PI * tanhf(w[2]);
        float ct = cosf(0.5f * theta), st = sinf(0.5f * theta);
        float a  = 0.5f * (phi + omega), bb = 0.5f * (phi - omega);
        float ca = cosf(a), sa = sinf(a), cb = cosf(bb), sb = sinf(bb);
        f2* g = sG + t * 8;
        g[0] = (f2){ ca * ct,  ca * ct};  g[1] = (f2){ sa * ct,  -sa * ct};
        g[2] = (f2){-cb * st, -cb * st};  g[3] = (f2){ sb * st,  -sb * st};
        g[4] = (f2){ cb * st,  cb * st};  g[5] = (f2){ sb * st,  -sb * st};
        g[6] = (f2){ ca * ct,  ca * ct};  g[7] = (f2){-sa * ct,   sa * ct};
    }

    // ---- image load + wave norm; stage raw psi in LDS ----
    float* psi = (float*)sS;
    const f4* img4 = (const f4*)(image + (size_t)b * NPIX);
    f4 xs[4];
    float ss = 0.f;
    #pragma unroll
    for (int k = 0; k < 4; ++k) {
        xs[k] = img4[L + 64 * k];
        ss += xs[k].x * xs[k].x + xs[k].y * xs[k].y
            + xs[k].z * xs[k].z + xs[k].w * xs[k].w;
    }
    #pragma unroll
    for (int o = 32; o >= 1; o >>= 1) ss += __shfl_xor(ss, o, 64);
    const float inv = 1.0f / sqrtf(ss);
    #pragma unroll
    for (int k = 0; k < 4; ++k) *(f4*)&psi[(L + 64 * k) * 4] = xs[k];
    asm volatile("s_waitcnt lgkmcnt(0)" ::: "memory");

    // ---- init + RX(label, wire10=amp bit0) folded; canonical layout ----
    const float lab = label[b];
    const float clp =  cosf(0.5f * lab) * inv;
    const float slp = -sinf(0.5f * lab) * inv;
    const bool odd = L & 1;
    f2 X[32];
    #pragma unroll
    for (int j = 0; j < 32; ++j) {
        float pv = psi[(j << 5) | (L >> 1)];
        X[j] = odd ? (f2){0.f, slp * pv} : (f2){clp * pv, 0.f};
    }
    asm volatile("s_waitcnt lgkmcnt(0)" ::: "memory");

    const bool hi4 = (L >> 4) & 1;

    // ---- 8 layers ----
    for (int l = 0; l < NL; ++l) {
        const f2* G = sG + l * NW * 8;

        // wires 0..4 on reg bits (amp 10..6)
        gateR<16>(X, G + 0 * 8);
        gateR< 8>(X, G + 1 * 8);
        gateR< 4>(X, G + 2 * 8);
        gateR< 2>(X, G + 3 * 8);
        gateR< 1>(X, G + 4 * 8);

        // swap amp10(L5) <-> amp5(j4); then wire 5 on regs
        #pragma unroll
        for (int j = 0; j < 16; ++j) swap32(X[j], X[j + 16]);
        gateR<16>(X, G + 5 * 8);

        // swap amp9(L4) <-> amp4(j3); then wire 6 on regs
        #pragma unroll
        for (int jj = 0; jj < 16; ++jj) {
            int j = (jj & 7) | ((jj >> 3) << 4);
            swapX(X[j], X[j + 8], hi4, 16);
        }
        gateR<8>(X, G + 6 * 8);

        // wires 7..10 on lane bits 3..0 via DPP butterflies
        gateL<3, 0>(X, G + 7 * 8, L);   // amp3, lane^8
        gateL<2, 1>(X, G + 8 * 8, L);   // amp2, lane^4
        gateL<1, 2>(X, G + 9 * 8, L);   // amp1, lane^2
        gateL<0, 3>(X, G + 10 * 8, L);  // amp0, lane^1

        // ---- CNOT-ring permutation via LDS scatter (store e at F_l(e)) ----
        // current layout: regs j4..j0 = amp {5,4,8,7,6}; lanes L5..L0 = amp
        // {10,9,3,2,1,0}
        const int* C = ft.C[l];
        int FL = 0;
        FL ^= ((L >> 5) & 1) ? C[10] : 0;
        FL ^= ((L >> 4) & 1) ? C[9]  : 0;
        FL ^= ((L >> 3) & 1) ? C[3]  : 0;
        FL ^= ((L >> 2) & 1) ? C[2]  : 0;
        FL ^= ((L >> 1) & 1) ? C[1]  : 0;
        FL ^= ( L       & 1) ? C[0]  : 0;
        const int c5 = C[5], c4 = C[4], c8 = C[8], c7 = C[7], c6 = C[6];
        #pragma unroll
        for (int j = 0; j < 32; ++j) {
            int fr = ((j & 16) ? c5 : 0) ^ ((j & 8) ? c4 : 0)
                   ^ ((j & 4)  ? c8 : 0) ^ ((j & 2) ? c7 : 0)
                   ^ ((j & 1)  ? c6 : 0);
            sS[FL ^ fr] = X[j];
        }
        asm volatile("s_waitcnt lgkmcnt(0)" ::: "memory");
        __builtin_amdgcn_sched_barrier(0);
        // gather back canonical: X[j] = state[(j<<6)|L]
        #pragma unroll
        for (int j = 0; j < 32; ++j) X[j] = sS[(j << 6) | L];
        asm volatile("s_waitcnt lgkmcnt(0)" ::: "memory");
        __builtin_amdgcn_sched_barrier(0);
    }

    // ---- output: |amp[2p]|^2 * NPIX, p = (j<<5)|(L>>1) (even lanes) ----
    if (!odd) {
        float* ob = out + (size_t)b * NPIX + (L >> 1);
        #pragma unroll
        for (int j = 0; j < 32; ++j) {
            f2 a = X[j];
            ob[j << 5] = (a.x * a.x + a.y * a.y) * (float)NPIX;
        }
    }
}

extern "C" void kernel_launch(void* const* d_in, const int* in_sizes, int n_in,
                              void* d_out, int out_size, void* d_ws, size_t ws_size,
                              hipStream_t stream) {
    const float* image   = (const float*)d_in[0];
    const float* label   = (const float*)d_in[1];
    const float* weights = (const float*)d_in[2];
    float* out = (float*)d_out;

    FTab ft;
    for (int l = 0; l < NL; ++l)
        for (int bpos = 0; bpos < NW; ++bpos)
            ft.C[l][bpos] = fmap_h(1 << bpos, l + 1);   // r = l%(NW-1)+1 = l+1

    int batch = in_sizes[1];  // 1024
    pqc_kernel<<<batch, 64, 0, stream>>>(image, label, weights, out, ft);
}